// Round 10
// baseline (144.885 us; speedup 1.0000x reference)
//
#include <hip/hip_runtime.h>
#include <hip/hip_fp16.h>

#define D_IN  128
#define D_HID 128
#define D_OUT 64
#define NBMAX 512      // max buckets (N <= 65536; packed formats assume this)
#define CHUNK 2048     // edges per k_bucket block
#define FCACHE 3072    // k_fin LDS edge cache (bucket mean ~2046, max ~2300)

typedef __attribute__((ext_vector_type(8))) short bf16x8;
typedef __attribute__((ext_vector_type(4))) float f32x4;

__device__ __forceinline__ unsigned short f2bf_rne(float f) {
    unsigned int u = __float_as_uint(f);
    return (unsigned short)((u + 0x7FFFu + ((u >> 16) & 1u)) >> 16);
}

// ---------------------------------------------------------------- zero counters
__global__ void k_zero(int* __restrict__ cntD, int* __restrict__ cntS, int NB) {
    const int t = threadIdx.x;
    if (t < NB) { cntD[t] = 0; cntS[t] = 0; }
}

// ---------------------------------------------------------------- bucket scatter
__launch_bounds__(256)
__global__ void k_bucket(const int* __restrict__ src, const int* __restrict__ dst,
                         int E, int NB, int cap,
                         int* __restrict__ cntD, int* __restrict__ cntS,
                         unsigned int* __restrict__ storeD, unsigned char* __restrict__ storeS) {
    __shared__ int lcD[NBMAX], lcS[NBMAX];
    __shared__ int lbD[NBMAX], lbS[NBMAX];
    const int t = threadIdx.x;
    const int e0 = blockIdx.x * CHUNK;
    const int e1 = min(e0 + CHUNK, E);

    for (int i = t; i < NB; i += 256) { lcD[i] = 0; lcS[i] = 0; }
    __syncthreads();
    for (int i = e0 + t; i < e1; i += 256) {
        atomicAdd(&lcD[dst[i] >> 7], 1);
        atomicAdd(&lcS[src[i] >> 7], 1);
    }
    __syncthreads();
    for (int i = t; i < NB; i += 256) {
        lbD[i] = lcD[i] ? atomicAdd(&cntD[i], lcD[i]) : 0;
        lbS[i] = lcS[i] ? atomicAdd(&cntS[i], lcS[i]) : 0;
        lcD[i] = 0; lcS[i] = 0;
    }
    __syncthreads();
    for (int i = e0 + t; i < e1; i += 256) {
        const int s = src[i], d = dst[i];
        const int bd = d >> 7;
        const int pd = lbD[bd] + atomicAdd(&lcD[bd], 1);
        storeD[(long long)bd * cap + pd] = (unsigned int)s | ((unsigned int)(d & 127) << 16);
        const int bs = s >> 7;
        const int ps = lbS[bs] + atomicAdd(&lcS[bs], 1);
        storeS[(long long)bs * cap + ps] = (unsigned char)(s & 127);
    }
}

// ---------------------------------------------------------------- finalize (scan fused)
__launch_bounds__(256)
__global__ void k_fin(const unsigned int* __restrict__ storeD, const unsigned char* __restrict__ storeS,
                      const int* __restrict__ cntD, const int* __restrict__ cntS,
                      int cap, int N, int NB, int E,
                      int* __restrict__ rowptr, float* __restrict__ inv_in,
                      float* __restrict__ inv_out, unsigned short* __restrict__ csr_src) {
    __shared__ int fh[128];
    __shared__ int sc[128];
    __shared__ int cur[128];
    __shared__ int red[256];
    __shared__ unsigned int ecache[FCACHE];
    const int b = blockIdx.x, t = threadIdx.x;
    const long long sb = (long long)b * cap;

    int partial = 0;
    for (int i = t; i < b; i += 256) partial += cntD[i];
    red[t] = partial;
    __syncthreads();
    for (int off = 128; off > 0; off >>= 1) {
        if (t < off) red[t] += red[t + off];
        __syncthreads();
    }
    const int base = red[0];

    const int cnt = cntD[b];
    const bool cached = (cnt <= FCACHE);
    if (cached) {
        for (int i = t; i < cnt; i += 256) ecache[i] = storeD[sb + i];
    }

    if (t < 128) fh[t] = 0;
    __syncthreads();
    for (int i = t; i < cnt; i += 256) {
        const unsigned int e = cached ? ecache[i] : storeD[sb + i];
        atomicAdd(&fh[e >> 16], 1);
    }
    __syncthreads();
    if (t < 128) sc[t] = fh[t];
    __syncthreads();
    int inc = (t < 128) ? sc[t] : 0;
    for (int off = 1; off < 128; off <<= 1) {
        int o = (t >= off && t < 128) ? sc[t - off] : 0;
        __syncthreads();
        if (t < 128) { inc += o; sc[t] = inc; }
        __syncthreads();
    }
    if (t < 128) {
        const int excl = inc - fh[t];
        cur[t] = excl;
        const int node = (b << 7) + t;
        if (node < N) {
            rowptr[node] = base + excl;
            inv_in[node] = rsqrtf((float)max(fh[t], 1));
        }
    }
    if (b == NB - 1 && t == 128) rowptr[N] = E;
    __syncthreads();
    for (int i = t; i < cnt; i += 256) {
        const unsigned int e = cached ? ecache[i] : storeD[sb + i];
        const int pos = atomicAdd(&cur[e >> 16], 1);
        csr_src[base + pos] = (unsigned short)(e & 0xFFFFu);
    }

    __syncthreads();
    if (t < 128) fh[t] = 0;
    __syncthreads();
    const int cnts = cntS[b];
    for (int i = t; i < cnts; i += 256) atomicAdd(&fh[storeS[sb + i]], 1);
    __syncthreads();
    if (t < 128) {
        const int node = (b << 7) + t;
        if (node < N) inv_out[node] = rsqrtf((float)max(fh[t], 1));
    }
}

// ---------------------------------------------------------------- MFMA GEMM (split-bf16)
// Y[i][j] = (half) sum_k A[i][k]*scale_i*W[k][j];  A fp32 or fp16, K=128.
// Block: 32 rows x 64 cols, 256 thr = 4 waves; wave (wr,wc)=(w>>1,w&1) does
// 16 rows x 32 cols = 2 MFMA n-tiles. A split hi/lo bf16; 3 products.
// Frag layout (verified m89/m93): A lane l: row=l&15, k=(l>>4)*8+i (contig 8);
// B stored [col][k]; C/D: row=(l>>4)*4+i, col=l&15.
template<int LDN, typename TA>
__launch_bounds__(256)
__global__ void k_gemm_mfma(const TA* __restrict__ X, const float* __restrict__ W,
                            const float* __restrict__ scale, __half* __restrict__ Y, int N) {
    __shared__ short Ah[32][136], Al[32][136];   // +8 pad: 2-way-max conflicts, 16B aligned
    __shared__ short Bh[64][136], Bl[64][136];

    const int t = threadIdx.x;
    const int row0 = blockIdx.x * 32;
    const int col0 = blockIdx.y * 64;

    // ---- stage A (32 x 128) as hi/lo bf16
    if constexpr (sizeof(TA) == 4) {
#pragma unroll
        for (int p = 0; p < 4; ++p) {
            const int idx = p * 256 + t;          // 0..1023 float4 units
            const int r   = idx >> 5;
            const int c4  = (idx & 31) << 2;
            const int gr  = row0 + r;
            float4 v = make_float4(0.f, 0.f, 0.f, 0.f);
            if (gr < N) {
                v = *(const float4*)((const float*)X + (long long)gr * 128 + c4);
                if (scale) { const float s = scale[gr]; v.x *= s; v.y *= s; v.z *= s; v.w *= s; }
            }
            const float f[4] = {v.x, v.y, v.z, v.w};
            short4 h, l;
            short hh[4], ll[4];
#pragma unroll
            for (int i = 0; i < 4; ++i) {
                const unsigned short hb = f2bf_rne(f[i]);
                const float hf = __uint_as_float(((unsigned int)hb) << 16);
                hh[i] = (short)hb;
                ll[i] = (short)f2bf_rne(f[i] - hf);
            }
            h = make_short4(hh[0], hh[1], hh[2], hh[3]);
            l = make_short4(ll[0], ll[1], ll[2], ll[3]);
            *(short4*)&Ah[r][c4] = h;
            *(short4*)&Al[r][c4] = l;
        }
    } else {
#pragma unroll
        for (int p = 0; p < 2; ++p) {
            const int idx = p * 256 + t;          // 0..511 half8 units
            const int r   = idx >> 4;
            const int c8  = (idx & 15) << 3;
            const int gr  = row0 + r;
            uint4 raw = make_uint4(0u, 0u, 0u, 0u);
            if (gr < N) raw = *(const uint4*)((const __half*)X + (long long)gr * 128 + c8);
            const __half2* hp = (const __half2*)&raw;
            short hh[8], ll[8];
#pragma unroll
            for (int u = 0; u < 4; ++u) {
                const float2 f2 = __half22float2(hp[u]);
                const float f[2] = {f2.x, f2.y};
#pragma unroll
                for (int q = 0; q < 2; ++q) {
                    const unsigned short hb = f2bf_rne(f[q]);
                    const float hf = __uint_as_float(((unsigned int)hb) << 16);
                    hh[2 * u + q] = (short)hb;
                    ll[2 * u + q] = (short)f2bf_rne(f[q] - hf);
                }
            }
            *(short4*)&Ah[r][c8]     = make_short4(hh[0], hh[1], hh[2], hh[3]);
            *(short4*)&Ah[r][c8 + 4] = make_short4(hh[4], hh[5], hh[6], hh[7]);
            *(short4*)&Al[r][c8]     = make_short4(ll[0], ll[1], ll[2], ll[3]);
            *(short4*)&Al[r][c8 + 4] = make_short4(ll[4], ll[5], ll[6], ll[7]);
        }
    }

    // ---- stage B (128 x 64 slice of W) transposed: Bs[col][k]
#pragma unroll
    for (int p = 0; p < 8; ++p) {
        const int idx = p * 256 + t;              // 0..2047 float4 units
        const int k   = idx >> 4;
        const int c4  = (idx & 15) << 2;
        const float4 v = *(const float4*)(W + (long long)k * LDN + col0 + c4);
        const float f[4] = {v.x, v.y, v.z, v.w};
#pragma unroll
        for (int i = 0; i < 4; ++i) {
            const unsigned short hb = f2bf_rne(f[i]);
            const float hf = __uint_as_float(((unsigned int)hb) << 16);
            Bh[c4 + i][k] = (short)hb;
            Bl[c4 + i][k] = (short)f2bf_rne(f[i] - hf);
        }
    }
    __syncthreads();

    // ---- MFMA
    const int w    = t >> 6;
    const int lane = t & 63;
    const int wr = w >> 1, wc = w & 1;
    const int lrow = lane & 15;
    const int lk   = (lane >> 4) << 3;

    f32x4 acc0 = {0.f, 0.f, 0.f, 0.f};
    f32x4 acc1 = {0.f, 0.f, 0.f, 0.f};
#pragma unroll
    for (int ks = 0; ks < 4; ++ks) {
        const int k = ks * 32 + lk;
        const bf16x8 ah  = *(const bf16x8*)&Ah[wr * 16 + lrow][k];
        const bf16x8 al  = *(const bf16x8*)&Al[wr * 16 + lrow][k];
        const bf16x8 bh0 = *(const bf16x8*)&Bh[wc * 32 + lrow][k];
        const bf16x8 bl0 = *(const bf16x8*)&Bl[wc * 32 + lrow][k];
        const bf16x8 bh1 = *(const bf16x8*)&Bh[wc * 32 + 16 + lrow][k];
        const bf16x8 bl1 = *(const bf16x8*)&Bl[wc * 32 + 16 + lrow][k];
        acc0 = __builtin_amdgcn_mfma_f32_16x16x32_bf16(ah, bh0, acc0, 0, 0, 0);
        acc0 = __builtin_amdgcn_mfma_f32_16x16x32_bf16(ah, bl0, acc0, 0, 0, 0);
        acc0 = __builtin_amdgcn_mfma_f32_16x16x32_bf16(al, bh0, acc0, 0, 0, 0);
        acc1 = __builtin_amdgcn_mfma_f32_16x16x32_bf16(ah, bh1, acc1, 0, 0, 0);
        acc1 = __builtin_amdgcn_mfma_f32_16x16x32_bf16(ah, bl1, acc1, 0, 0, 0);
        acc1 = __builtin_amdgcn_mfma_f32_16x16x32_bf16(al, bh1, acc1, 0, 0, 0);
    }

    // ---- epilogue: D row=(lane>>4)*4+i, col=lane&15
#pragma unroll
    for (int i = 0; i < 4; ++i) {
        const int r = row0 + wr * 16 + ((lane >> 4) << 2) + i;
        if (r < N) {
            Y[(long long)r * LDN + col0 + wc * 32 + lrow]      = __float2half(acc0[i]);
            Y[(long long)r * LDN + col0 + wc * 32 + 16 + lrow] = __float2half(acc1[i]);
        }
    }
}

// ---------------------------------------------------------------- CSR gather (fp16 rows, fp32 accum)
// One wave per destination node; 8 halves (16B) per lane; 4-deep MLP unroll.
template<int D, bool RELU, typename TO>
__launch_bounds__(256)
__global__ void k_gather(const int* __restrict__ rowptr, const unsigned short* __restrict__ csr_src,
                         const __half* __restrict__ Y, const float* __restrict__ inv_in,
                         const float* __restrict__ inv_out, const float* __restrict__ b,
                         TO* __restrict__ out, int N) {
    const int wid  = (int)((blockIdx.x * 256u + threadIdx.x) >> 6);
    const int lane = threadIdx.x & 63;
    if (wid >= N) return;

    const int start = rowptr[wid];
    const int end   = rowptr[wid + 1];

    constexpr int LPE = D / 8;            // lanes per edge (16 or 8)
    constexpr int EPW = 64 / LPE;         // edges per group (4 or 8)
    const int grp  = lane / LPE;
    const int colh = (lane % LPE) * 8;

    float a[8];
#pragma unroll
    for (int u = 0; u < 8; ++u) a[u] = 0.0f;

    auto accum = [&](uint4 raw) {
        const __half2* h = (const __half2*)&raw;
#pragma unroll
        for (int u = 0; u < 4; ++u) {
            const float2 f = __half22float2(h[u]);
            a[2 * u]     += f.x;
            a[2 * u + 1] += f.y;
        }
    };

    for (int k = start; k < end; k += 64) {
        const int idx = k + lane;
        const int sv  = (idx < end) ? (int)csr_src[idx] : 0;
        const int cnt = min(64, end - k);
        int j = 0;
        for (; j + 4 * EPW <= cnt; j += 4 * EPW) {
            const int s0 = __shfl(sv, j + grp);
            const int s1 = __shfl(sv, j + EPW + grp);
            const int s2 = __shfl(sv, j + 2 * EPW + grp);
            const int s3 = __shfl(sv, j + 3 * EPW + grp);
            const uint4 r0 = *(const uint4*)(Y + (long long)s0 * D + colh);
            const uint4 r1 = *(const uint4*)(Y + (long long)s1 * D + colh);
            const uint4 r2 = *(const uint4*)(Y + (long long)s2 * D + colh);
            const uint4 r3 = *(const uint4*)(Y + (long long)s3 * D + colh);
            accum(r0); accum(r1); accum(r2); accum(r3);
        }
        for (; j < cnt; j += EPW) {
            const int jj = j + grp;
            const int s  = __shfl(sv, jj);
            if (jj < cnt) {
                const uint4 r = *(const uint4*)(Y + (long long)s * D + colh);
                accum(r);
            }
        }
    }

#pragma unroll
    for (int u = 0; u < 8; ++u) a[u] += __shfl_down(a[u], 32);
#pragma unroll
    for (int u = 0; u < 8; ++u) a[u] += __shfl_down(a[u], 16);
    if (EPW == 8) {
#pragma unroll
        for (int u = 0; u < 8; ++u) a[u] += __shfl_down(a[u], 8);
    }

    if (lane < LPE) {
        const float ii = inv_in[wid];
        const float io = RELU ? inv_out[wid] : 0.0f;
        const float4 b0 = *(const float4*)(b + colh);
        const float4 b1 = *(const float4*)(b + colh + 4);
        float r[8];
        r[0] = a[0] * ii + b0.x; r[1] = a[1] * ii + b0.y;
        r[2] = a[2] * ii + b0.z; r[3] = a[3] * ii + b0.w;
        r[4] = a[4] * ii + b1.x; r[5] = a[5] * ii + b1.y;
        r[6] = a[6] * ii + b1.z; r[7] = a[7] * ii + b1.w;
        if (RELU) {
#pragma unroll
            for (int u = 0; u < 8; ++u) r[u] = fmaxf(r[u], 0.0f) * io;
        }
        if constexpr (sizeof(TO) == 2) {
            __half2 h0 = __float22half2_rn(make_float2(r[0], r[1]));
            __half2 h1 = __float22half2_rn(make_float2(r[2], r[3]));
            __half2 h2 = __float22half2_rn(make_float2(r[4], r[5]));
            __half2 h3 = __float22half2_rn(make_float2(r[6], r[7]));
            uint4 pk;
            pk.x = *(unsigned int*)&h0; pk.y = *(unsigned int*)&h1;
            pk.z = *(unsigned int*)&h2; pk.w = *(unsigned int*)&h3;
            *(uint4*)((__half*)out + (long long)wid * D + colh) = pk;
        } else {
            float* o = (float*)out + (long long)wid * D + colh;
            *(float4*)(o)     = make_float4(r[0], r[1], r[2], r[3]);
            *(float4*)(o + 4) = make_float4(r[4], r[5], r[6], r[7]);
        }
    }
}

// ---------------------------------------------------------------- launch
extern "C" void kernel_launch(void* const* d_in, const int* in_sizes, int n_in,
                              void* d_out, int out_size, void* d_ws, size_t ws_size,
                              hipStream_t stream) {
    const int*   src = (const int*)d_in[0];
    const int*   dst = (const int*)d_in[1];
    const float* x   = (const float*)d_in[2];
    const float* W1  = (const float*)d_in[3];
    const float* b1  = (const float*)d_in[4];
    const float* W2  = (const float*)d_in[5];
    const float* b2  = (const float*)d_in[6];
    float* out = (float*)d_out;

    const int E  = in_sizes[0];
    const int N  = in_sizes[2] / D_IN;
    const int NB = (N + 127) >> 7;                 // 128-node buckets (<= NBMAX)
    const int mean = E / NB;
    const int cap  = mean + mean / 4 + 128;        // generous multinomial margin

    char* ws = (char*)d_ws;
    size_t off = 0;
    auto alloc = [&](size_t bytes) -> void* {
        void* p = ws + off;
        off += (bytes + 255) & ~(size_t)255;
        return p;
    };
    float*          inv_out = (float*)alloc((size_t)N * 4);
    float*          inv_in  = (float*)alloc((size_t)N * 4);
    int*            rowptr  = (int*)alloc((size_t)(N + 1) * 4);
    int*            cntD    = (int*)alloc((size_t)NB * 4);
    int*            cntS    = (int*)alloc((size_t)NB * 4);
    unsigned int*   storeD  = (unsigned int*)alloc((size_t)NB * cap * 4);
    unsigned char*  storeS  = (unsigned char*)alloc((size_t)NB * cap);
    unsigned short* csr_src = (unsigned short*)alloc((size_t)E * 2);
    __half*         Y1      = (__half*)alloc((size_t)N * D_HID * 2);
    __half*         H       = (__half*)alloc((size_t)N * D_HID * 2);
    __half*         Y2      = (__half*)alloc((size_t)N * D_OUT * 2);
    (void)ws_size; (void)n_in; (void)out_size;

    // CSR build + degree norms (counting sort, LDS-aggregated)
    k_zero<<<1, 512, 0, stream>>>(cntD, cntS, NB);
    k_bucket<<<(E + CHUNK - 1) / CHUNK, 256, 0, stream>>>(src, dst, E, NB, cap, cntD, cntS, storeD, storeS);
    k_fin<<<NB, 256, 0, stream>>>(storeD, storeS, cntD, cntS, cap, N, NB, E,
                                  rowptr, inv_in, inv_out, csr_src);

    // layer 1: Y1 = (x*inv_out)@W1 ; H = (half) relu(gather(Y1)*inv_in + b1) * inv_out
    {
        dim3 g((N + 31) / 32, D_HID / 64);
        k_gemm_mfma<D_HID, float><<<g, 256, 0, stream>>>(x, W1, inv_out, Y1, N);
    }
    k_gather<D_HID, true, __half><<<(N + 3) / 4, 256, 0, stream>>>(rowptr, csr_src, Y1, inv_in, inv_out, b1, H, N);

    // layer 2: Y2 = H@W2 ; out = gather(Y2)*inv_in + b2
    {
        dim3 g((N + 31) / 32, D_OUT / 64);
        k_gemm_mfma<D_OUT, __half><<<g, 256, 0, stream>>>(H, W2, nullptr, Y2, N);
    }
    k_gather<D_OUT, false, float><<<(N + 3) / 4, 256, 0, stream>>>(rowptr, csr_src, Y2, inv_in, nullptr, b2, out, N);
}

// Round 11
// 142.290 us; speedup vs baseline: 1.0182x; 1.0182x over previous
//
#include <hip/hip_runtime.h>
#include <hip/hip_fp16.h>

#define D_IN  128
#define D_HID 128
#define D_OUT 64
#define NBMAX 512      // max buckets (N <= 65536; packed formats assume this)
#define CHUNK 2048     // edges per k_bucket block
#define FCACHE 3072    // k_fin LDS edge cache (bucket mean ~2046, max ~2300)

typedef __attribute__((ext_vector_type(8))) short bf16x8;
typedef __attribute__((ext_vector_type(4))) float f32x4;

__device__ __forceinline__ unsigned short f2bf_rne(float f) {
    unsigned int u = __float_as_uint(f);
    return (unsigned short)((u + 0x7FFFu + ((u >> 16) & 1u)) >> 16);
}

// ---------------------------------------------------------------- prep:
// split W1/W2 to transposed hi/lo bf16 (B-frag-ready [j][k]) + zero counters.
__launch_bounds__(256)
__global__ void k_prep(const float* __restrict__ W1, const float* __restrict__ W2,
                       unsigned short* __restrict__ W1h, unsigned short* __restrict__ W1l,
                       unsigned short* __restrict__ W2h, unsigned short* __restrict__ W2l,
                       int* __restrict__ cntD, int* __restrict__ cntS, int NB) {
    const int b = blockIdx.x, t = threadIdx.x;
    if (b < 64) {                       // W1: 128x128
        const int i = b * 256 + t;      // i = k*128 + j
        const int k = i >> 7, j = i & 127;
        const float v = W1[i];
        const unsigned short hb = f2bf_rne(v);
        const float hf = __uint_as_float((unsigned int)hb << 16);
        W1h[j * 128 + k] = hb;
        W1l[j * 128 + k] = f2bf_rne(v - hf);
    } else if (b < 96) {                // W2: 128x64
        const int i = (b - 64) * 256 + t;   // i = k*64 + j
        const int k = i >> 6, j = i & 63;
        const float v = W2[i];
        const unsigned short hb = f2bf_rne(v);
        const float hf = __uint_as_float((unsigned int)hb << 16);
        W2h[j * 128 + k] = hb;
        W2l[j * 128 + k] = f2bf_rne(v - hf);
    } else {
        for (int i = t; i < NB; i += 256) { cntD[i] = 0; cntS[i] = 0; }
    }
}

// ---------------------------------------------------------------- bucket scatter
// Counting-sort pass 1; edges read ONCE into registers, replayed for placement.
__launch_bounds__(256)
__global__ void k_bucket(const int* __restrict__ src, const int* __restrict__ dst,
                         int E, int NB, int cap,
                         int* __restrict__ cntD, int* __restrict__ cntS,
                         unsigned int* __restrict__ storeD, unsigned char* __restrict__ storeS) {
    __shared__ int lcD[NBMAX], lcS[NBMAX];
    __shared__ int lbD[NBMAX], lbS[NBMAX];
    const int t = threadIdx.x;
    const int e0 = blockIdx.x * CHUNK;
    const int e1 = min(e0 + CHUNK, E);

    int sv[8], dv[8];
#pragma unroll
    for (int u = 0; u < 8; ++u) {
        const int i = e0 + u * 256 + t;
        if (i < e1) { sv[u] = src[i]; dv[u] = dst[i]; }
        else        { sv[u] = -1;     dv[u] = -1; }
    }

    for (int i = t; i < NB; i += 256) { lcD[i] = 0; lcS[i] = 0; }
    __syncthreads();
#pragma unroll
    for (int u = 0; u < 8; ++u) {
        if (sv[u] >= 0) {
            atomicAdd(&lcD[dv[u] >> 7], 1);
            atomicAdd(&lcS[sv[u] >> 7], 1);
        }
    }
    __syncthreads();
    for (int i = t; i < NB; i += 256) {
        lbD[i] = lcD[i] ? atomicAdd(&cntD[i], lcD[i]) : 0;
        lbS[i] = lcS[i] ? atomicAdd(&cntS[i], lcS[i]) : 0;
        lcD[i] = 0; lcS[i] = 0;
    }
    __syncthreads();
#pragma unroll
    for (int u = 0; u < 8; ++u) {
        if (sv[u] >= 0) {
            const int s = sv[u], d = dv[u];
            const int bd = d >> 7;
            const int pd = lbD[bd] + atomicAdd(&lcD[bd], 1);
            storeD[(long long)bd * cap + pd] = (unsigned int)s | ((unsigned int)(d & 127) << 16);
            const int bs = s >> 7;
            const int ps = lbS[bs] + atomicAdd(&lcS[bs], 1);
            storeS[(long long)bs * cap + ps] = (unsigned char)(s & 127);
        }
    }
}

// ---------------------------------------------------------------- finalize (scan fused)
__launch_bounds__(256)
__global__ void k_fin(const unsigned int* __restrict__ storeD, const unsigned char* __restrict__ storeS,
                      const int* __restrict__ cntD, const int* __restrict__ cntS,
                      int cap, int N, int NB, int E,
                      int* __restrict__ rowptr, float* __restrict__ inv_in,
                      float* __restrict__ inv_out, unsigned short* __restrict__ csr_src) {
    __shared__ int fh[128];
    __shared__ int sc[128];
    __shared__ int cur[128];
    __shared__ int red[256];
    __shared__ unsigned int ecache[FCACHE];
    const int b = blockIdx.x, t = threadIdx.x;
    const long long sb = (long long)b * cap;

    int partial = 0;
    for (int i = t; i < b; i += 256) partial += cntD[i];
    red[t] = partial;
    __syncthreads();
    for (int off = 128; off > 0; off >>= 1) {
        if (t < off) red[t] += red[t + off];
        __syncthreads();
    }
    const int base = red[0];

    const int cnt = cntD[b];
    const bool cached = (cnt <= FCACHE);
    if (cached) {
        for (int i = t; i < cnt; i += 256) ecache[i] = storeD[sb + i];
    }

    if (t < 128) fh[t] = 0;
    __syncthreads();
    for (int i = t; i < cnt; i += 256) {
        const unsigned int e = cached ? ecache[i] : storeD[sb + i];
        atomicAdd(&fh[e >> 16], 1);
    }
    __syncthreads();
    if (t < 128) sc[t] = fh[t];
    __syncthreads();
    int inc = (t < 128) ? sc[t] : 0;
    for (int off = 1; off < 128; off <<= 1) {
        int o = (t >= off && t < 128) ? sc[t - off] : 0;
        __syncthreads();
        if (t < 128) { inc += o; sc[t] = inc; }
        __syncthreads();
    }
    if (t < 128) {
        const int excl = inc - fh[t];
        cur[t] = excl;
        const int node = (b << 7) + t;
        if (node < N) {
            rowptr[node] = base + excl;
            inv_in[node] = rsqrtf((float)max(fh[t], 1));
        }
    }
    if (b == NB - 1 && t == 128) rowptr[N] = E;
    __syncthreads();
    for (int i = t; i < cnt; i += 256) {
        const unsigned int e = cached ? ecache[i] : storeD[sb + i];
        const int pos = atomicAdd(&cur[e >> 16], 1);
        csr_src[base + pos] = (unsigned short)(e & 0xFFFFu);
    }

    __syncthreads();
    if (t < 128) fh[t] = 0;
    __syncthreads();
    const int cnts = cntS[b];
    for (int i = t; i < cnts; i += 256) atomicAdd(&fh[storeS[sb + i]], 1);
    __syncthreads();
    if (t < 128) {
        const int node = (b << 7) + t;
        if (node < N) inv_out[node] = rsqrtf((float)max(fh[t], 1));
    }
}

// ---------------------------------------------------------------- MFMA GEMM (split-bf16, pre-split W)
// Y[i][j] = (half) sum_k A[i][k]*scale_i*W[k][j];  A fp32 or fp16, K=128.
// Block: 32 rows x LDN cols, 4 waves: wave w -> rows (w&1)*16, cols (w>>1)*(LDN/2).
// A split hi/lo bf16 in LDS; B-frags loaded straight from pre-split global Wt[j][k].
// Frag layout (m89/m93): A lane l: row=l&15, k=(l>>4)*8+i; B same with col=l&15;
// C/D: row=(l>>4)*4+i, col=l&15.
template<int LDN, typename TA>
__launch_bounds__(256)
__global__ void k_gemm_mfma(const TA* __restrict__ X,
                            const unsigned short* __restrict__ Wth,
                            const unsigned short* __restrict__ Wtl,
                            const float* __restrict__ scale, __half* __restrict__ Y, int N) {
    __shared__ short Ah[32][136], Al[32][136];

    const int t = threadIdx.x;
    const int row0 = blockIdx.x * 32;

    // ---- stage A (32 x 128) as hi/lo bf16
    if constexpr (sizeof(TA) == 4) {
#pragma unroll
        for (int p = 0; p < 4; ++p) {
            const int idx = p * 256 + t;          // float4 units
            const int r   = idx >> 5;
            const int c4  = (idx & 31) << 2;
            const int gr  = row0 + r;
            float4 v = make_float4(0.f, 0.f, 0.f, 0.f);
            if (gr < N) {
                v = *(const float4*)((const float*)X + (long long)gr * 128 + c4);
                if (scale) { const float s = scale[gr]; v.x *= s; v.y *= s; v.z *= s; v.w *= s; }
            }
            const float f[4] = {v.x, v.y, v.z, v.w};
            short hh[4], ll[4];
#pragma unroll
            for (int i = 0; i < 4; ++i) {
                const unsigned short hb = f2bf_rne(f[i]);
                const float hf = __uint_as_float(((unsigned int)hb) << 16);
                hh[i] = (short)hb;
                ll[i] = (short)f2bf_rne(f[i] - hf);
            }
            *(short4*)&Ah[r][c4] = make_short4(hh[0], hh[1], hh[2], hh[3]);
            *(short4*)&Al[r][c4] = make_short4(ll[0], ll[1], ll[2], ll[3]);
        }
    } else {
#pragma unroll
        for (int p = 0; p < 2; ++p) {
            const int idx = p * 256 + t;          // half8 units
            const int r   = idx >> 4;
            const int c8  = (idx & 15) << 3;
            const int gr  = row0 + r;
            uint4 raw = make_uint4(0u, 0u, 0u, 0u);
            if (gr < N) raw = *(const uint4*)((const __half*)X + (long long)gr * 128 + c8);
            const __half2* hp = (const __half2*)&raw;
            short hh[8], ll[8];
#pragma unroll
            for (int u = 0; u < 4; ++u) {
                const float2 f2 = __half22float2(hp[u]);
                const float f[2] = {f2.x, f2.y};
#pragma unroll
                for (int q = 0; q < 2; ++q) {
                    const unsigned short hb = f2bf_rne(f[q]);
                    const float hf = __uint_as_float(((unsigned int)hb) << 16);
                    hh[2 * u + q] = (short)hb;
                    ll[2 * u + q] = (short)f2bf_rne(f[q] - hf);
                }
            }
            *(short4*)&Ah[r][c8]     = make_short4(hh[0], hh[1], hh[2], hh[3]);
            *(short4*)&Ah[r][c8 + 4] = make_short4(hh[4], hh[5], hh[6], hh[7]);
            *(short4*)&Al[r][c8]     = make_short4(ll[0], ll[1], ll[2], ll[3]);
            *(short4*)&Al[r][c8 + 4] = make_short4(ll[4], ll[5], ll[6], ll[7]);
        }
    }
    __syncthreads();

    // ---- MFMA: wave tiles
    constexpr int NT = LDN / 32;                  // n-subtiles per wave (4 or 2)
    const int w    = t >> 6;
    const int lane = t & 63;
    const int rg = w & 1, cg = w >> 1;
    const int lrow = lane & 15;
    const int lk   = (lane >> 4) << 3;
    const int colbase = cg * (16 * NT);

    f32x4 acc[NT];
#pragma unroll
    for (int n = 0; n < NT; ++n) acc[n] = (f32x4){0.f, 0.f, 0.f, 0.f};

#pragma unroll
    for (int ks = 0; ks < 4; ++ks) {
        const int k = ks * 32 + lk;
        const bf16x8 ah = *(const bf16x8*)&Ah[rg * 16 + lrow][k];
        const bf16x8 al = *(const bf16x8*)&Al[rg * 16 + lrow][k];
#pragma unroll
        for (int n = 0; n < NT; ++n) {
            const int col = colbase + n * 16 + lrow;
            const bf16x8 bh = *(const bf16x8*)(Wth + (size_t)col * 128 + k);
            const bf16x8 bl = *(const bf16x8*)(Wtl + (size_t)col * 128 + k);
            acc[n] = __builtin_amdgcn_mfma_f32_16x16x32_bf16(ah, bh, acc[n], 0, 0, 0);
            acc[n] = __builtin_amdgcn_mfma_f32_16x16x32_bf16(ah, bl, acc[n], 0, 0, 0);
            acc[n] = __builtin_amdgcn_mfma_f32_16x16x32_bf16(al, bh, acc[n], 0, 0, 0);
        }
    }

    // ---- epilogue: D row=(lane>>4)*4+i, col=lane&15
#pragma unroll
    for (int n = 0; n < NT; ++n) {
#pragma unroll
        for (int i = 0; i < 4; ++i) {
            const int r = row0 + rg * 16 + ((lane >> 4) << 2) + i;
            if (r < N)
                Y[(long long)r * LDN + colbase + n * 16 + lrow] = __float2half(acc[n][i]);
        }
    }
}

// ---------------------------------------------------------------- CSR gather (fp16 rows, fp32 accum)
// One wave per destination node; 8 halves (16B) per lane; 4-deep MLP unroll.
template<int D, bool RELU, typename TO>
__launch_bounds__(256)
__global__ void k_gather(const int* __restrict__ rowptr, const unsigned short* __restrict__ csr_src,
                         const __half* __restrict__ Y, const float* __restrict__ inv_in,
                         const float* __restrict__ inv_out, const float* __restrict__ b,
                         TO* __restrict__ out, int N) {
    const int wid  = (int)((blockIdx.x * 256u + threadIdx.x) >> 6);
    const int lane = threadIdx.x & 63;
    if (wid >= N) return;

    const int start = rowptr[wid];
    const int end   = rowptr[wid + 1];

    constexpr int LPE = D / 8;            // lanes per edge (16 or 8)
    constexpr int EPW = 64 / LPE;         // edges per group (4 or 8)
    const int grp  = lane / LPE;
    const int colh = (lane % LPE) * 8;

    float a[8];
#pragma unroll
    for (int u = 0; u < 8; ++u) a[u] = 0.0f;

    auto accum = [&](uint4 raw) {
        const __half2* h = (const __half2*)&raw;
#pragma unroll
        for (int u = 0; u < 4; ++u) {
            const float2 f = __half22float2(h[u]);
            a[2 * u]     += f.x;
            a[2 * u + 1] += f.y;
        }
    };

    for (int k = start; k < end; k += 64) {
        const int idx = k + lane;
        const int sv  = (idx < end) ? (int)csr_src[idx] : 0;
        const int cnt = min(64, end - k);
        int j = 0;
        for (; j + 4 * EPW <= cnt; j += 4 * EPW) {
            const int s0 = __shfl(sv, j + grp);
            const int s1 = __shfl(sv, j + EPW + grp);
            const int s2 = __shfl(sv, j + 2 * EPW + grp);
            const int s3 = __shfl(sv, j + 3 * EPW + grp);
            const uint4 r0 = *(const uint4*)(Y + (long long)s0 * D + colh);
            const uint4 r1 = *(const uint4*)(Y + (long long)s1 * D + colh);
            const uint4 r2 = *(const uint4*)(Y + (long long)s2 * D + colh);
            const uint4 r3 = *(const uint4*)(Y + (long long)s3 * D + colh);
            accum(r0); accum(r1); accum(r2); accum(r3);
        }
        for (; j < cnt; j += EPW) {
            const int jj = j + grp;
            const int s  = __shfl(sv, jj);
            if (jj < cnt) {
                const uint4 r = *(const uint4*)(Y + (long long)s * D + colh);
                accum(r);
            }
        }
    }

#pragma unroll
    for (int u = 0; u < 8; ++u) a[u] += __shfl_down(a[u], 32);
#pragma unroll
    for (int u = 0; u < 8; ++u) a[u] += __shfl_down(a[u], 16);
    if (EPW == 8) {
#pragma unroll
        for (int u = 0; u < 8; ++u) a[u] += __shfl_down(a[u], 8);
    }

    if (lane < LPE) {
        const float ii = inv_in[wid];
        const float io = RELU ? inv_out[wid] : 0.0f;
        const float4 b0 = *(const float4*)(b + colh);
        const float4 b1 = *(const float4*)(b + colh + 4);
        float r[8];
        r[0] = a[0] * ii + b0.x; r[1] = a[1] * ii + b0.y;
        r[2] = a[2] * ii + b0.z; r[3] = a[3] * ii + b0.w;
        r[4] = a[4] * ii + b1.x; r[5] = a[5] * ii + b1.y;
        r[6] = a[6] * ii + b1.z; r[7] = a[7] * ii + b1.w;
        if (RELU) {
#pragma unroll
            for (int u = 0; u < 8; ++u) r[u] = fmaxf(r[u], 0.0f) * io;
        }
        if constexpr (sizeof(TO) == 2) {
            __half2 h0 = __float22half2_rn(make_float2(r[0], r[1]));
            __half2 h1 = __float22half2_rn(make_float2(r[2], r[3]));
            __half2 h2 = __float22half2_rn(make_float2(r[4], r[5]));
            __half2 h3 = __float22half2_rn(make_float2(r[6], r[7]));
            uint4 pk;
            pk.x = *(unsigned int*)&h0; pk.y = *(unsigned int*)&h1;
            pk.z = *(unsigned int*)&h2; pk.w = *(unsigned int*)&h3;
            *(uint4*)((__half*)out + (long long)wid * D + colh) = pk;
        } else {
            float* o = (float*)out + (long long)wid * D + colh;
            *(float4*)(o)     = make_float4(r[0], r[1], r[2], r[3]);
            *(float4*)(o + 4) = make_float4(r[4], r[5], r[6], r[7]);
        }
    }
}

// ---------------------------------------------------------------- launch
extern "C" void kernel_launch(void* const* d_in, const int* in_sizes, int n_in,
                              void* d_out, int out_size, void* d_ws, size_t ws_size,
                              hipStream_t stream) {
    const int*   src = (const int*)d_in[0];
    const int*   dst = (const int*)d_in[1];
    const float* x   = (const float*)d_in[2];
    const float* W1  = (const float*)d_in[3];
    const float* b1  = (const float*)d_in[4];
    const float* W2  = (const float*)d_in[5];
    const float* b2  = (const float*)d_in[6];
    float* out = (float*)d_out;

    const int E  = in_sizes[0];
    const int N  = in_sizes[2] / D_IN;
    const int NB = (N + 127) >> 7;                 // 128-node buckets (<= NBMAX)
    const int mean = E / NB;
    const int cap  = mean + mean / 4 + 128;        // generous multinomial margin

    char* ws = (char*)d_ws;
    size_t off = 0;
    auto alloc = [&](size_t bytes) -> void* {
        void* p = ws + off;
        off += (bytes + 255) & ~(size_t)255;
        return p;
    };
    float*          inv_out = (float*)alloc((size_t)N * 4);
    float*          inv_in  = (float*)alloc((size_t)N * 4);
    int*            rowptr  = (int*)alloc((size_t)(N + 1) * 4);
    int*            cntD    = (int*)alloc((size_t)NB * 4);
    int*            cntS    = (int*)alloc((size_t)NB * 4);
    unsigned int*   storeD  = (unsigned int*)alloc((size_t)NB * cap * 4);
    unsigned char*  storeS  = (unsigned char*)alloc((size_t)NB * cap);
    unsigned short* csr_src = (unsigned short*)alloc((size_t)E * 2);
    unsigned short* W1h     = (unsigned short*)alloc(128 * 128 * 2);
    unsigned short* W1l     = (unsigned short*)alloc(128 * 128 * 2);
    unsigned short* W2h     = (unsigned short*)alloc(64 * 128 * 2);
    unsigned short* W2l     = (unsigned short*)alloc(64 * 128 * 2);
    __half*         Y1      = (__half*)alloc((size_t)N * D_HID * 2);
    __half*         H       = (__half*)alloc((size_t)N * D_HID * 2);
    __half*         Y2      = (__half*)alloc((size_t)N * D_OUT * 2);
    (void)ws_size; (void)n_in; (void)out_size;

    // prep (W split + counter zero) + CSR build + degree norms
    k_prep<<<97, 256, 0, stream>>>(W1, W2, W1h, W1l, W2h, W2l, cntD, cntS, NB);
    k_bucket<<<(E + CHUNK - 1) / CHUNK, 256, 0, stream>>>(src, dst, E, NB, cap, cntD, cntS, storeD, storeS);
    k_fin<<<NB, 256, 0, stream>>>(storeD, storeS, cntD, cntS, cap, N, NB, E,
                                  rowptr, inv_in, inv_out, csr_src);

    // layer 1: Y1 = (x*inv_out)@W1 ; H = (half) relu(gather(Y1)*inv_in + b1) * inv_out
    k_gemm_mfma<D_HID, float><<<(N + 31) / 32, 256, 0, stream>>>(x, W1h, W1l, inv_out, Y1, N);
    k_gather<D_HID, true, __half><<<(N + 3) / 4, 256, 0, stream>>>(rowptr, csr_src, Y1, inv_in, inv_out, b1, H, N);

    // layer 2: Y2 = H@W2 ; out = gather(Y2)*inv_in + b2
    k_gemm_mfma<D_OUT, __half><<<(N + 31) / 32, 256, 0, stream>>>(H, W2h, W2l, nullptr, Y2, N);
    k_gather<D_OUT, false, float><<<(N + 3) / 4, 256, 0, stream>>>(rowptr, csr_src, Y2, inv_in, nullptr, b2, out, N);
}

// Round 12
// 140.866 us; speedup vs baseline: 1.0285x; 1.0101x over previous
//
#include <hip/hip_runtime.h>
#include <hip/hip_fp16.h>

#define D_IN  128
#define D_HID 128
#define D_OUT 64
#define NBMAX 512      // max buckets (N <= 65536; packed formats assume this)
#define CHUNK 2048     // edges per k_bucket block
#define FCACHE 3072    // k_fin LDS edge cache (bucket mean ~2046, max ~2300)

typedef __attribute__((ext_vector_type(8))) short bf16x8;
typedef __attribute__((ext_vector_type(4))) float f32x4;

__device__ __forceinline__ unsigned short f2bf_rne(float f) {
    unsigned int u = __float_as_uint(f);
    return (unsigned short)((u + 0x7FFFu + ((u >> 16) & 1u)) >> 16);
}

// ---------------------------------------------------------------- prep:
// split W1/W2 to transposed hi/lo bf16 (B-frag-ready [j][k]) + zero counters.
__launch_bounds__(256)
__global__ void k_prep(const float* __restrict__ W1, const float* __restrict__ W2,
                       unsigned short* __restrict__ W1h, unsigned short* __restrict__ W1l,
                       unsigned short* __restrict__ W2h, unsigned short* __restrict__ W2l,
                       int* __restrict__ cntD, int* __restrict__ cntS, int NB) {
    const int b = blockIdx.x, t = threadIdx.x;
    if (b < 64) {                       // W1: 128x128
        const int i = b * 256 + t;      // i = k*128 + j
        const int k = i >> 7, j = i & 127;
        const float v = W1[i];
        const unsigned short hb = f2bf_rne(v);
        const float hf = __uint_as_float((unsigned int)hb << 16);
        W1h[j * 128 + k] = hb;
        W1l[j * 128 + k] = f2bf_rne(v - hf);
    } else if (b < 96) {                // W2: 128x64
        const int i = (b - 64) * 256 + t;   // i = k*64 + j
        const int k = i >> 6, j = i & 63;
        const float v = W2[i];
        const unsigned short hb = f2bf_rne(v);
        const float hf = __uint_as_float((unsigned int)hb << 16);
        W2h[j * 128 + k] = hb;
        W2l[j * 128 + k] = f2bf_rne(v - hf);
    } else {
        for (int i = t; i < NB; i += 256) { cntD[i] = 0; cntS[i] = 0; }
    }
}

// ---------------------------------------------------------------- bucket scatter
// Counting-sort pass 1 with block-local LDS sort: histogram -> LDS scan ->
// LDS-sorted staging (payload + final global position) -> near-coalesced flush.
__launch_bounds__(256)
__global__ void k_bucket(const int* __restrict__ src, const int* __restrict__ dst,
                         int E, int NB, int cap,
                         int* __restrict__ cntD, int* __restrict__ cntS,
                         unsigned int* __restrict__ storeD, unsigned char* __restrict__ storeS) {
    __shared__ int lc[512], ls[512];        // counts, then cursors
    __shared__ int baD[512], baS[512];      // local exclusive bases
    __shared__ int gbD[512], gbS[512];      // global linear base per bucket
    __shared__ int ssum[256];
    __shared__ unsigned int  ldsD[CHUNK];
    __shared__ int           gposD[CHUNK];
    __shared__ unsigned char ldsS[CHUNK];
    __shared__ int           gposS[CHUNK];

    const int t = threadIdx.x;
    const int e0 = blockIdx.x * CHUNK;
    const int e1 = min(e0 + CHUNK, E);
    const int n  = e1 - e0;

    int sv[8], dv[8];
#pragma unroll
    for (int u = 0; u < 8; ++u) {
        const int i = e0 + u * 256 + t;
        if (i < e1) { sv[u] = src[i]; dv[u] = dst[i]; }
        else        { sv[u] = -1;     dv[u] = -1; }
    }

    lc[t] = 0; lc[t + 256] = 0; ls[t] = 0; ls[t + 256] = 0;
    __syncthreads();
#pragma unroll
    for (int u = 0; u < 8; ++u) {
        if (sv[u] >= 0) {
            atomicAdd(&lc[dv[u] >> 7], 1);
            atomicAdd(&ls[sv[u] >> 7], 1);
        }
    }
    __syncthreads();

    // two-level exclusive scans (512 bins, thread t owns bins 2t, 2t+1)
    const int c0 = lc[2 * t], c1 = lc[2 * t + 1];
    const int s0 = ls[2 * t], s1 = ls[2 * t + 1];
    // D scan
    {
        const int pc = c0 + c1;
        ssum[t] = pc; __syncthreads();
        int inc = pc;
        for (int off = 1; off < 256; off <<= 1) {
            const int o = (t >= off) ? ssum[t - off] : 0;
            __syncthreads();
            inc += o; ssum[t] = inc;
            __syncthreads();
        }
        const int ex = inc - pc;
        baD[2 * t] = ex; baD[2 * t + 1] = ex + c0;
    }
    // S scan
    {
        const int ps = s0 + s1;
        ssum[t] = ps; __syncthreads();
        int inc = ps;
        for (int off = 1; off < 256; off <<= 1) {
            const int o = (t >= off) ? ssum[t - off] : 0;
            __syncthreads();
            inc += o; ssum[t] = inc;
            __syncthreads();
        }
        const int ex = inc - ps;
        baS[2 * t] = ex; baS[2 * t + 1] = ex + s0;
    }
    __syncthreads();

    // reserve global ranges (linear index incl. bucket stride)
    for (int i = t; i < NB; i += 256) {
        const int c = lc[i];
        gbD[i] = i * cap + (c ? atomicAdd(&cntD[i], c) : 0);
        const int s = ls[i];
        gbS[i] = i * cap + (s ? atomicAdd(&cntS[i], s) : 0);
    }
    __syncthreads();
    lc[t] = 0; lc[t + 256] = 0; ls[t] = 0; ls[t + 256] = 0;
    __syncthreads();

    // place into LDS-sorted buffers
#pragma unroll
    for (int u = 0; u < 8; ++u) {
        if (sv[u] >= 0) {
            const int s = sv[u], d = dv[u];
            const int bd = d >> 7;
            const int lp = atomicAdd(&lc[bd], 1);
            const int p  = baD[bd] + lp;
            ldsD[p]  = (unsigned int)s | ((unsigned int)(d & 127) << 16);
            gposD[p] = gbD[bd] + lp;
            const int bs = s >> 7;
            const int lq = atomicAdd(&ls[bs], 1);
            const int q  = baS[bs] + lq;
            ldsS[q]  = (unsigned char)(s & 127);
            gposS[q] = gbS[bs] + lq;
        }
    }
    __syncthreads();

    // flush (runs of same bucket are contiguous -> near-coalesced)
    for (int p = t; p < n; p += 256) {
        storeD[gposD[p]] = ldsD[p];
        storeS[gposS[p]] = ldsS[p];
    }
}

// ---------------------------------------------------------------- finalize (scan fused)
__launch_bounds__(256)
__global__ void k_fin(const unsigned int* __restrict__ storeD, const unsigned char* __restrict__ storeS,
                      const int* __restrict__ cntD, const int* __restrict__ cntS,
                      int cap, int N, int NB, int E,
                      int* __restrict__ rowptr, float* __restrict__ inv_in,
                      float* __restrict__ inv_out, unsigned short* __restrict__ csr_src) {
    __shared__ int fh[128];
    __shared__ int sc[128];
    __shared__ int cur[128];
    __shared__ int red[256];
    __shared__ unsigned int ecache[FCACHE];
    const int b = blockIdx.x, t = threadIdx.x;
    const long long sb = (long long)b * cap;

    int partial = 0;
    for (int i = t; i < b; i += 256) partial += cntD[i];
    red[t] = partial;
    __syncthreads();
    for (int off = 128; off > 0; off >>= 1) {
        if (t < off) red[t] += red[t + off];
        __syncthreads();
    }
    const int base = red[0];

    const int cnt = cntD[b];
    const bool cached = (cnt <= FCACHE);
    if (cached) {
        for (int i = t; i < cnt; i += 256) ecache[i] = storeD[sb + i];
    }

    if (t < 128) fh[t] = 0;
    __syncthreads();
    for (int i = t; i < cnt; i += 256) {
        const unsigned int e = cached ? ecache[i] : storeD[sb + i];
        atomicAdd(&fh[e >> 16], 1);
    }
    __syncthreads();
    if (t < 128) sc[t] = fh[t];
    __syncthreads();
    int inc = (t < 128) ? sc[t] : 0;
    for (int off = 1; off < 128; off <<= 1) {
        int o = (t >= off && t < 128) ? sc[t - off] : 0;
        __syncthreads();
        if (t < 128) { inc += o; sc[t] = inc; }
        __syncthreads();
    }
    if (t < 128) {
        const int excl = inc - fh[t];
        cur[t] = excl;
        const int node = (b << 7) + t;
        if (node < N) {
            rowptr[node] = base + excl;
            inv_in[node] = rsqrtf((float)max(fh[t], 1));
        }
    }
    if (b == NB - 1 && t == 128) rowptr[N] = E;
    __syncthreads();
    for (int i = t; i < cnt; i += 256) {
        const unsigned int e = cached ? ecache[i] : storeD[sb + i];
        const int pos = atomicAdd(&cur[e >> 16], 1);
        csr_src[base + pos] = (unsigned short)(e & 0xFFFFu);
    }

    __syncthreads();
    if (t < 128) fh[t] = 0;
    __syncthreads();
    const int cnts = cntS[b];
    for (int i = t; i < cnts; i += 256) atomicAdd(&fh[storeS[sb + i]], 1);
    __syncthreads();
    if (t < 128) {
        const int node = (b << 7) + t;
        if (node < N) inv_out[node] = rsqrtf((float)max(fh[t], 1));
    }
}

// ---------------------------------------------------------------- MFMA GEMM (split-bf16, pre-split W)
// Y[i][j] = (half) sum_k A[i][k]*scale_i*W[k][j];  A fp32 or fp16, K=128.
// Block: 32 rows x LDN cols, 4 waves: wave w -> rows (w&1)*16, cols (w>>1)*(LDN/2).
// A split hi/lo bf16 in LDS; B-frags loaded straight from pre-split global Wt[j][k].
template<int LDN, typename TA>
__launch_bounds__(256)
__global__ void k_gemm_mfma(const TA* __restrict__ X,
                            const unsigned short* __restrict__ Wth,
                            const unsigned short* __restrict__ Wtl,
                            const float* __restrict__ scale, __half* __restrict__ Y, int N) {
    __shared__ short Ah[32][136], Al[32][136];

    const int t = threadIdx.x;
    const int row0 = blockIdx.x * 32;

    if constexpr (sizeof(TA) == 4) {
#pragma unroll
        for (int p = 0; p < 4; ++p) {
            const int idx = p * 256 + t;          // float4 units
            const int r   = idx >> 5;
            const int c4  = (idx & 31) << 2;
            const int gr  = row0 + r;
            float4 v = make_float4(0.f, 0.f, 0.f, 0.f);
            if (gr < N) {
                v = *(const float4*)((const float*)X + (long long)gr * 128 + c4);
                if (scale) { const float s = scale[gr]; v.x *= s; v.y *= s; v.z *= s; v.w *= s; }
            }
            const float f[4] = {v.x, v.y, v.z, v.w};
            short hh[4], ll[4];
#pragma unroll
            for (int i = 0; i < 4; ++i) {
                const unsigned short hb = f2bf_rne(f[i]);
                const float hf = __uint_as_float(((unsigned int)hb) << 16);
                hh[i] = (short)hb;
                ll[i] = (short)f2bf_rne(f[i] - hf);
            }
            *(short4*)&Ah[r][c4] = make_short4(hh[0], hh[1], hh[2], hh[3]);
            *(short4*)&Al[r][c4] = make_short4(ll[0], ll[1], ll[2], ll[3]);
        }
    } else {
#pragma unroll
        for (int p = 0; p < 2; ++p) {
            const int idx = p * 256 + t;          // half8 units
            const int r   = idx >> 4;
            const int c8  = (idx & 15) << 3;
            const int gr  = row0 + r;
            uint4 raw = make_uint4(0u, 0u, 0u, 0u);
            if (gr < N) raw = *(const uint4*)((const __half*)X + (long long)gr * 128 + c8);
            const __half2* hp = (const __half2*)&raw;
            short hh[8], ll[8];
#pragma unroll
            for (int u = 0; u < 4; ++u) {
                const float2 f2 = __half22float2(hp[u]);
                const float f[2] = {f2.x, f2.y};
#pragma unroll
                for (int q = 0; q < 2; ++q) {
                    const unsigned short hb = f2bf_rne(f[q]);
                    const float hf = __uint_as_float(((unsigned int)hb) << 16);
                    hh[2 * u + q] = (short)hb;
                    ll[2 * u + q] = (short)f2bf_rne(f[q] - hf);
                }
            }
            *(short4*)&Ah[r][c8]     = make_short4(hh[0], hh[1], hh[2], hh[3]);
            *(short4*)&Ah[r][c8 + 4] = make_short4(hh[4], hh[5], hh[6], hh[7]);
            *(short4*)&Al[r][c8]     = make_short4(ll[0], ll[1], ll[2], ll[3]);
            *(short4*)&Al[r][c8 + 4] = make_short4(ll[4], ll[5], ll[6], ll[7]);
        }
    }
    __syncthreads();

    constexpr int NT = LDN / 32;                  // n-subtiles per wave (4 or 2)
    const int w    = t >> 6;
    const int lane = t & 63;
    const int rg = w & 1, cg = w >> 1;
    const int lrow = lane & 15;
    const int lk   = (lane >> 4) << 3;
    const int colbase = cg * (16 * NT);

    f32x4 acc[NT];
#pragma unroll
    for (int n = 0; n < NT; ++n) acc[n] = (f32x4){0.f, 0.f, 0.f, 0.f};

#pragma unroll
    for (int ks = 0; ks < 4; ++ks) {
        const int k = ks * 32 + lk;
        const bf16x8 ah = *(const bf16x8*)&Ah[rg * 16 + lrow][k];
        const bf16x8 al = *(const bf16x8*)&Al[rg * 16 + lrow][k];
#pragma unroll
        for (int n = 0; n < NT; ++n) {
            const int col = colbase + n * 16 + lrow;
            const bf16x8 bh = *(const bf16x8*)(Wth + (size_t)col * 128 + k);
            const bf16x8 bl = *(const bf16x8*)(Wtl + (size_t)col * 128 + k);
            acc[n] = __builtin_amdgcn_mfma_f32_16x16x32_bf16(ah, bh, acc[n], 0, 0, 0);
            acc[n] = __builtin_amdgcn_mfma_f32_16x16x32_bf16(ah, bl, acc[n], 0, 0, 0);
            acc[n] = __builtin_amdgcn_mfma_f32_16x16x32_bf16(al, bh, acc[n], 0, 0, 0);
        }
    }

#pragma unroll
    for (int n = 0; n < NT; ++n) {
#pragma unroll
        for (int i = 0; i < 4; ++i) {
            const int r = row0 + rg * 16 + ((lane >> 4) << 2) + i;
            if (r < N)
                Y[(long long)r * LDN + colbase + n * 16 + lrow] = __float2half(acc[n][i]);
        }
    }
}

// ---------------------------------------------------------------- CSR gather (fp16 rows, fp32 accum)
// One wave per destination node; 8 halves (16B) per lane; 8-deep MLP unroll.
template<int D, bool RELU, typename TO>
__launch_bounds__(256)
__global__ void k_gather(const int* __restrict__ rowptr, const unsigned short* __restrict__ csr_src,
                         const __half* __restrict__ Y, const float* __restrict__ inv_in,
                         const float* __restrict__ inv_out, const float* __restrict__ b,
                         TO* __restrict__ out, int N) {
    const int wid  = (int)((blockIdx.x * 256u + threadIdx.x) >> 6);
    const int lane = threadIdx.x & 63;
    if (wid >= N) return;

    const int start = rowptr[wid];
    const int end   = rowptr[wid + 1];

    constexpr int LPE = D / 8;            // lanes per edge (16 or 8)
    constexpr int EPW = 64 / LPE;         // edges per group (4 or 8)
    const int grp  = lane / LPE;
    const int colh = (lane % LPE) * 8;

    float a[8];
#pragma unroll
    for (int u = 0; u < 8; ++u) a[u] = 0.0f;

    auto accum = [&](uint4 raw) {
        const __half2* h = (const __half2*)&raw;
#pragma unroll
        for (int u = 0; u < 4; ++u) {
            const float2 f = __half22float2(h[u]);
            a[2 * u]     += f.x;
            a[2 * u + 1] += f.y;
        }
    };

    for (int k = start; k < end; k += 64) {
        const int idx = k + lane;
        const int sv  = (idx < end) ? (int)csr_src[idx] : 0;
        const int cnt = min(64, end - k);
        int j = 0;
        // 8 independent row loads in flight
        for (; j + 8 * EPW <= cnt; j += 8 * EPW) {
            int s[8];
#pragma unroll
            for (int u = 0; u < 8; ++u) s[u] = __shfl(sv, j + u * EPW + grp);
            uint4 r[8];
#pragma unroll
            for (int u = 0; u < 8; ++u) r[u] = *(const uint4*)(Y + (long long)s[u] * D + colh);
#pragma unroll
            for (int u = 0; u < 8; ++u) accum(r[u]);
        }
        for (; j + 4 * EPW <= cnt; j += 4 * EPW) {
            int s[4];
#pragma unroll
            for (int u = 0; u < 4; ++u) s[u] = __shfl(sv, j + u * EPW + grp);
            uint4 r[4];
#pragma unroll
            for (int u = 0; u < 4; ++u) r[u] = *(const uint4*)(Y + (long long)s[u] * D + colh);
#pragma unroll
            for (int u = 0; u < 4; ++u) accum(r[u]);
        }
        for (; j < cnt; j += EPW) {
            const int jj = j + grp;
            const int s  = __shfl(sv, jj);
            if (jj < cnt) {
                const uint4 r = *(const uint4*)(Y + (long long)s * D + colh);
                accum(r);
            }
        }
    }

#pragma unroll
    for (int u = 0; u < 8; ++u) a[u] += __shfl_down(a[u], 32);
#pragma unroll
    for (int u = 0; u < 8; ++u) a[u] += __shfl_down(a[u], 16);
    if (EPW == 8) {
#pragma unroll
        for (int u = 0; u < 8; ++u) a[u] += __shfl_down(a[u], 8);
    }

    if (lane < LPE) {
        const float ii = inv_in[wid];
        const float io = RELU ? inv_out[wid] : 0.0f;
        const float4 b0 = *(const float4*)(b + colh);
        const float4 b1 = *(const float4*)(b + colh + 4);
        float r[8];
        r[0] = a[0] * ii + b0.x; r[1] = a[1] * ii + b0.y;
        r[2] = a[2] * ii + b0.z; r[3] = a[3] * ii + b0.w;
        r[4] = a[4] * ii + b1.x; r[5] = a[5] * ii + b1.y;
        r[6] = a[6] * ii + b1.z; r[7] = a[7] * ii + b1.w;
        if (RELU) {
#pragma unroll
            for (int u = 0; u < 8; ++u) r[u] = fmaxf(r[u], 0.0f) * io;
        }
        if constexpr (sizeof(TO) == 2) {
            __half2 h0 = __float22half2_rn(make_float2(r[0], r[1]));
            __half2 h1 = __float22half2_rn(make_float2(r[2], r[3]));
            __half2 h2 = __float22half2_rn(make_float2(r[4], r[5]));
            __half2 h3 = __float22half2_rn(make_float2(r[6], r[7]));
            uint4 pk;
            pk.x = *(unsigned int*)&h0; pk.y = *(unsigned int*)&h1;
            pk.z = *(unsigned int*)&h2; pk.w = *(unsigned int*)&h3;
            *(uint4*)((__half*)out + (long long)wid * D + colh) = pk;
        } else {
            float* o = (float*)out + (long long)wid * D + colh;
            *(float4*)(o)     = make_float4(r[0], r[1], r[2], r[3]);
            *(float4*)(o + 4) = make_float4(r[4], r[5], r[6], r[7]);
        }
    }
}

// ---------------------------------------------------------------- launch
extern "C" void kernel_launch(void* const* d_in, const int* in_sizes, int n_in,
                              void* d_out, int out_size, void* d_ws, size_t ws_size,
                              hipStream_t stream) {
    const int*   src = (const int*)d_in[0];
    const int*   dst = (const int*)d_in[1];
    const float* x   = (const float*)d_in[2];
    const float* W1  = (const float*)d_in[3];
    const float* b1  = (const float*)d_in[4];
    const float* W2  = (const float*)d_in[5];
    const float* b2  = (const float*)d_in[6];
    float* out = (float*)d_out;

    const int E  = in_sizes[0];
    const int N  = in_sizes[2] / D_IN;
    const int NB = (N + 127) >> 7;                 // 128-node buckets (<= NBMAX)
    const int mean = E / NB;
    const int cap  = mean + mean / 4 + 128;        // generous multinomial margin

    char* ws = (char*)d_ws;
    size_t off = 0;
    auto alloc = [&](size_t bytes) -> void* {
        void* p = ws + off;
        off += (bytes + 255) & ~(size_t)255;
        return p;
    };
    float*          inv_out = (float*)alloc((size_t)N * 4);
    float*          inv_in  = (float*)alloc((size_t)N * 4);
    int*            rowptr  = (int*)alloc((size_t)(N + 1) * 4);
    int*            cntD    = (int*)alloc((size_t)NB * 4);
    int*            cntS    = (int*)alloc((size_t)NB * 4);
    unsigned int*   storeD  = (unsigned int*)alloc((size_t)NB * cap * 4);
    unsigned char*  storeS  = (unsigned char*)alloc((size_t)NB * cap);
    unsigned short* csr_src = (unsigned short*)alloc((size_t)E * 2);
    unsigned short* W1h     = (unsigned short*)alloc(128 * 128 * 2);
    unsigned short* W1l     = (unsigned short*)alloc(128 * 128 * 2);
    unsigned short* W2h     = (unsigned short*)alloc(64 * 128 * 2);
    unsigned short* W2l     = (unsigned short*)alloc(64 * 128 * 2);
    __half*         Y1      = (__half*)alloc((size_t)N * D_HID * 2);
    __half*         H       = (__half*)alloc((size_t)N * D_HID * 2);
    __half*         Y2      = (__half*)alloc((size_t)N * D_OUT * 2);
    (void)ws_size; (void)n_in; (void)out_size;

    // prep (W split + counter zero) + CSR build + degree norms
    k_prep<<<97, 256, 0, stream>>>(W1, W2, W1h, W1l, W2h, W2l, cntD, cntS, NB);
    k_bucket<<<(E + CHUNK - 1) / CHUNK, 256, 0, stream>>>(src, dst, E, NB, cap, cntD, cntS, storeD, storeS);
    k_fin<<<NB, 256, 0, stream>>>(storeD, storeS, cntD, cntS, cap, N, NB, E,
                                  rowptr, inv_in, inv_out, csr_src);

    // layer 1: Y1 = (x*inv_out)@W1 ; H = (half) relu(gather(Y1)*inv_in + b1) * inv_out
    k_gemm_mfma<D_HID, float><<<(N + 31) / 32, 256, 0, stream>>>(x, W1h, W1l, inv_out, Y1, N);
    k_gather<D_HID, true, __half><<<(N + 3) / 4, 256, 0, stream>>>(rowptr, csr_src, Y1, inv_in, inv_out, b1, H, N);

    // layer 2: Y2 = H@W2 ; out = gather(Y2)*inv_in + b2
    k_gemm_mfma<D_OUT, __half><<<(N + 31) / 32, 256, 0, stream>>>(H, W2h, W2l, nullptr, Y2, N);
    k_gather<D_OUT, false, float><<<(N + 3) / 4, 256, 0, stream>>>(rowptr, csr_src, Y2, inv_in, nullptr, b2, out, N);
}

// Round 13
// 134.088 us; speedup vs baseline: 1.0805x; 1.0505x over previous
//
#include <hip/hip_runtime.h>
#include <hip/hip_fp16.h>

#define D_IN  128
#define D_HID 128
#define D_OUT 64
#define NBMAX 512      // max buckets (N <= 65536; packed formats assume this)
#define CHUNK 2048     // edges per k_bucket block
#define FCACHE 3072    // k_fin LDS edge cache (bucket mean ~2046, max ~2300)

typedef __attribute__((ext_vector_type(8))) short bf16x8;
typedef __attribute__((ext_vector_type(4))) float f32x4;

__device__ __forceinline__ unsigned short f2bf_rne(float f) {
    unsigned int u = __float_as_uint(f);
    return (unsigned short)((u + 0x7FFFu + ((u >> 16) & 1u)) >> 16);
}

// ---------------------------------------------------------------- prep:
// split W1/W2 to transposed hi/lo bf16 (B-frag-ready [j][k]) + zero counters.
__launch_bounds__(256)
__global__ void k_prep(const float* __restrict__ W1, const float* __restrict__ W2,
                       unsigned short* __restrict__ W1h, unsigned short* __restrict__ W1l,
                       unsigned short* __restrict__ W2h, unsigned short* __restrict__ W2l,
                       int* __restrict__ cntD, int* __restrict__ cntS, int NB) {
    const int b = blockIdx.x, t = threadIdx.x;
    if (b < 64) {                       // W1: 128x128
        const int i = b * 256 + t;      // i = k*128 + j
        const int k = i >> 7, j = i & 127;
        const float v = W1[i];
        const unsigned short hb = f2bf_rne(v);
        const float hf = __uint_as_float((unsigned int)hb << 16);
        W1h[j * 128 + k] = hb;
        W1l[j * 128 + k] = f2bf_rne(v - hf);
    } else if (b < 96) {                // W2: 128x64
        const int i = (b - 64) * 256 + t;   // i = k*64 + j
        const int k = i >> 6, j = i & 63;
        const float v = W2[i];
        const unsigned short hb = f2bf_rne(v);
        const float hf = __uint_as_float((unsigned int)hb << 16);
        W2h[j * 128 + k] = hb;
        W2l[j * 128 + k] = f2bf_rne(v - hf);
    } else {
        for (int i = t; i < NB; i += 256) { cntD[i] = 0; cntS[i] = 0; }
    }
}

// ---------------------------------------------------------------- merged bucket + gemm1 LDS
struct BucketS {
    int lc[512], ls[512];
    int baD[512], baS[512];
    int gbD[512], gbS[512];
    int ssum[256];
    unsigned int  ldsD[CHUNK];
    int           gposD[CHUNK];
    unsigned char ldsS[CHUNK];
    int           gposS[CHUNK];
};
struct GemmS {
    short Ah[32][136];
    short Al[32][136];
};
union SMem { BucketS b; GemmS g; };

// ---- bucket body: counting-sort pass 1 with block-local LDS sort
__device__ __forceinline__ void bucket_body(
        BucketS& sm, int bx,
        const int* __restrict__ src, const int* __restrict__ dst,
        int E, int NB, int cap,
        int* __restrict__ cntD, int* __restrict__ cntS,
        unsigned int* __restrict__ storeD, unsigned char* __restrict__ storeS) {
    const int t = threadIdx.x;
    const int e0 = bx * CHUNK;
    const int e1 = min(e0 + CHUNK, E);
    const int n  = e1 - e0;

    int sv[8], dv[8];
#pragma unroll
    for (int u = 0; u < 8; ++u) {
        const int i = e0 + u * 256 + t;
        if (i < e1) { sv[u] = src[i]; dv[u] = dst[i]; }
        else        { sv[u] = -1;     dv[u] = -1; }
    }

    sm.lc[t] = 0; sm.lc[t + 256] = 0; sm.ls[t] = 0; sm.ls[t + 256] = 0;
    __syncthreads();
#pragma unroll
    for (int u = 0; u < 8; ++u) {
        if (sv[u] >= 0) {
            atomicAdd(&sm.lc[dv[u] >> 7], 1);
            atomicAdd(&sm.ls[sv[u] >> 7], 1);
        }
    }
    __syncthreads();

    const int c0 = sm.lc[2 * t], c1 = sm.lc[2 * t + 1];
    const int s0 = sm.ls[2 * t], s1 = sm.ls[2 * t + 1];
    {   // D scan
        const int pc = c0 + c1;
        sm.ssum[t] = pc; __syncthreads();
        int inc = pc;
        for (int off = 1; off < 256; off <<= 1) {
            const int o = (t >= off) ? sm.ssum[t - off] : 0;
            __syncthreads();
            inc += o; sm.ssum[t] = inc;
            __syncthreads();
        }
        const int ex = inc - pc;
        sm.baD[2 * t] = ex; sm.baD[2 * t + 1] = ex + c0;
    }
    {   // S scan
        const int ps = s0 + s1;
        sm.ssum[t] = ps; __syncthreads();
        int inc = ps;
        for (int off = 1; off < 256; off <<= 1) {
            const int o = (t >= off) ? sm.ssum[t - off] : 0;
            __syncthreads();
            inc += o; sm.ssum[t] = inc;
            __syncthreads();
        }
        const int ex = inc - ps;
        sm.baS[2 * t] = ex; sm.baS[2 * t + 1] = ex + s0;
    }
    __syncthreads();

    for (int i = t; i < NB; i += 256) {
        const int c = sm.lc[i];
        sm.gbD[i] = i * cap + (c ? atomicAdd(&cntD[i], c) : 0);
        const int s = sm.ls[i];
        sm.gbS[i] = i * cap + (s ? atomicAdd(&cntS[i], s) : 0);
    }
    __syncthreads();
    sm.lc[t] = 0; sm.lc[t + 256] = 0; sm.ls[t] = 0; sm.ls[t + 256] = 0;
    __syncthreads();

#pragma unroll
    for (int u = 0; u < 8; ++u) {
        if (sv[u] >= 0) {
            const int s = sv[u], d = dv[u];
            const int bd = d >> 7;
            const int lp = atomicAdd(&sm.lc[bd], 1);
            const int p  = sm.baD[bd] + lp;
            sm.ldsD[p]  = (unsigned int)s | ((unsigned int)(d & 127) << 16);
            sm.gposD[p] = sm.gbD[bd] + lp;
            const int bs = s >> 7;
            const int lq = atomicAdd(&sm.ls[bs], 1);
            const int q  = sm.baS[bs] + lq;
            sm.ldsS[q]  = (unsigned char)(s & 127);
            sm.gposS[q] = sm.gbS[bs] + lq;
        }
    }
    __syncthreads();

    for (int p = t; p < n; p += 256) {
        storeD[sm.gposD[p]] = sm.ldsD[p];
        storeS[sm.gposS[p]] = sm.ldsS[p];
    }
}

// ---- gemm1 body: Y1 = (half)(X @ W1), X fp32, unscaled (scale moved to gather)
__device__ __forceinline__ void gemm1_body(
        GemmS& sm, int bx,
        const float* __restrict__ X,
        const unsigned short* __restrict__ Wth, const unsigned short* __restrict__ Wtl,
        __half* __restrict__ Y, int N) {
    const int t = threadIdx.x;
    const int row0 = bx * 32;

#pragma unroll
    for (int p = 0; p < 4; ++p) {
        const int idx = p * 256 + t;          // float4 units
        const int r   = idx >> 5;
        const int c4  = (idx & 31) << 2;
        const int gr  = row0 + r;
        float4 v = make_float4(0.f, 0.f, 0.f, 0.f);
        if (gr < N) v = *(const float4*)(X + (long long)gr * 128 + c4);
        const float f[4] = {v.x, v.y, v.z, v.w};
        short hh[4], ll[4];
#pragma unroll
        for (int i = 0; i < 4; ++i) {
            const unsigned short hb = f2bf_rne(f[i]);
            const float hf = __uint_as_float(((unsigned int)hb) << 16);
            hh[i] = (short)hb;
            ll[i] = (short)f2bf_rne(f[i] - hf);
        }
        *(short4*)&sm.Ah[r][c4] = make_short4(hh[0], hh[1], hh[2], hh[3]);
        *(short4*)&sm.Al[r][c4] = make_short4(ll[0], ll[1], ll[2], ll[3]);
    }
    __syncthreads();

    constexpr int NT = 4;                     // 128 cols / 32
    const int w    = t >> 6;
    const int lane = t & 63;
    const int rg = w & 1, cg = w >> 1;
    const int lrow = lane & 15;
    const int lk   = (lane >> 4) << 3;
    const int colbase = cg * (16 * NT);

    f32x4 acc[NT];
#pragma unroll
    for (int n = 0; n < NT; ++n) acc[n] = (f32x4){0.f, 0.f, 0.f, 0.f};

#pragma unroll
    for (int ks = 0; ks < 4; ++ks) {
        const int k = ks * 32 + lk;
        const bf16x8 ah = *(const bf16x8*)&sm.Ah[rg * 16 + lrow][k];
        const bf16x8 al = *(const bf16x8*)&sm.Al[rg * 16 + lrow][k];
#pragma unroll
        for (int n = 0; n < NT; ++n) {
            const int col = colbase + n * 16 + lrow;
            const bf16x8 bh = *(const bf16x8*)(Wth + (size_t)col * 128 + k);
            const bf16x8 bl = *(const bf16x8*)(Wtl + (size_t)col * 128 + k);
            acc[n] = __builtin_amdgcn_mfma_f32_16x16x32_bf16(ah, bh, acc[n], 0, 0, 0);
            acc[n] = __builtin_amdgcn_mfma_f32_16x16x32_bf16(ah, bl, acc[n], 0, 0, 0);
            acc[n] = __builtin_amdgcn_mfma_f32_16x16x32_bf16(al, bh, acc[n], 0, 0, 0);
        }
    }

#pragma unroll
    for (int n = 0; n < NT; ++n) {
#pragma unroll
        for (int i = 0; i < 4; ++i) {
            const int r = row0 + rg * 16 + ((lane >> 4) << 2) + i;
            if (r < N)
                Y[(long long)r * D_HID + colbase + n * 16 + lrow] = __float2half(acc[n][i]);
        }
    }
}

// ---- merged dispatch: blocks [0, nbBlk) sort; [nbBlk, nbBlk+gemmBlk) gemm1
__launch_bounds__(256)
__global__ void k_bucket_gemm(const int* __restrict__ src, const int* __restrict__ dst,
                              int E, int NB, int cap,
                              int* __restrict__ cntD, int* __restrict__ cntS,
                              unsigned int* __restrict__ storeD, unsigned char* __restrict__ storeS,
                              const float* __restrict__ X,
                              const unsigned short* __restrict__ Wth,
                              const unsigned short* __restrict__ Wtl,
                              __half* __restrict__ Y, int N, int nbBlk) {
    __shared__ SMem sm;
    const int bx = (int)blockIdx.x;
    if (bx < nbBlk)
        bucket_body(sm.b, bx, src, dst, E, NB, cap, cntD, cntS, storeD, storeS);
    else
        gemm1_body(sm.g, bx - nbBlk, X, Wth, Wtl, Y, N);
}

// ---------------------------------------------------------------- finalize (scan fused)
__launch_bounds__(256)
__global__ void k_fin(const unsigned int* __restrict__ storeD, const unsigned char* __restrict__ storeS,
                      const int* __restrict__ cntD, const int* __restrict__ cntS,
                      int cap, int N, int NB, int E,
                      int* __restrict__ rowptr, float* __restrict__ inv_in,
                      float* __restrict__ inv_out, unsigned short* __restrict__ csr_src) {
    __shared__ int fh[128];
    __shared__ int sc[128];
    __shared__ int cur[128];
    __shared__ int red[256];
    __shared__ unsigned int ecache[FCACHE];
    const int b = blockIdx.x, t = threadIdx.x;
    const long long sb = (long long)b * cap;

    int partial = 0;
    for (int i = t; i < b; i += 256) partial += cntD[i];
    red[t] = partial;
    __syncthreads();
    for (int off = 128; off > 0; off >>= 1) {
        if (t < off) red[t] += red[t + off];
        __syncthreads();
    }
    const int base = red[0];

    const int cnt = cntD[b];
    const bool cached = (cnt <= FCACHE);
    if (cached) {
        for (int i = t; i < cnt; i += 256) ecache[i] = storeD[sb + i];
    }

    if (t < 128) fh[t] = 0;
    __syncthreads();
    for (int i = t; i < cnt; i += 256) {
        const unsigned int e = cached ? ecache[i] : storeD[sb + i];
        atomicAdd(&fh[e >> 16], 1);
    }
    __syncthreads();
    if (t < 128) sc[t] = fh[t];
    __syncthreads();
    int inc = (t < 128) ? sc[t] : 0;
    for (int off = 1; off < 128; off <<= 1) {
        int o = (t >= off && t < 128) ? sc[t - off] : 0;
        __syncthreads();
        if (t < 128) { inc += o; sc[t] = inc; }
        __syncthreads();
    }
    if (t < 128) {
        const int excl = inc - fh[t];
        cur[t] = excl;
        const int node = (b << 7) + t;
        if (node < N) {
            rowptr[node] = base + excl;
            inv_in[node] = rsqrtf((float)max(fh[t], 1));
        }
    }
    if (b == NB - 1 && t == 128) rowptr[N] = E;
    __syncthreads();
    for (int i = t; i < cnt; i += 256) {
        const unsigned int e = cached ? ecache[i] : storeD[sb + i];
        const int pos = atomicAdd(&cur[e >> 16], 1);
        csr_src[base + pos] = (unsigned short)(e & 0xFFFFu);
    }

    __syncthreads();
    if (t < 128) fh[t] = 0;
    __syncthreads();
    const int cnts = cntS[b];
    for (int i = t; i < cnts; i += 256) atomicAdd(&fh[storeS[sb + i]], 1);
    __syncthreads();
    if (t < 128) {
        const int node = (b << 7) + t;
        if (node < N) inv_out[node] = rsqrtf((float)max(fh[t], 1));
    }
}

// ---------------------------------------------------------------- MFMA GEMM (layer 2)
template<int LDN>
__launch_bounds__(256)
__global__ void k_gemm_mfma(const __half* __restrict__ X,
                            const unsigned short* __restrict__ Wth,
                            const unsigned short* __restrict__ Wtl,
                            __half* __restrict__ Y, int N) {
    __shared__ short Ah[32][136], Al[32][136];

    const int t = threadIdx.x;
    const int row0 = blockIdx.x * 32;

#pragma unroll
    for (int p = 0; p < 2; ++p) {
        const int idx = p * 256 + t;          // half8 units
        const int r   = idx >> 4;
        const int c8  = (idx & 15) << 3;
        const int gr  = row0 + r;
        uint4 raw = make_uint4(0u, 0u, 0u, 0u);
        if (gr < N) raw = *(const uint4*)(X + (long long)gr * 128 + c8);
        const __half2* hp = (const __half2*)&raw;
        short hh[8], ll[8];
#pragma unroll
        for (int u = 0; u < 4; ++u) {
            const float2 f2 = __half22float2(hp[u]);
            const float f[2] = {f2.x, f2.y};
#pragma unroll
            for (int q = 0; q < 2; ++q) {
                const unsigned short hb = f2bf_rne(f[q]);
                const float hf = __uint_as_float(((unsigned int)hb) << 16);
                hh[2 * u + q] = (short)hb;
                ll[2 * u + q] = (short)f2bf_rne(f[q] - hf);
            }
        }
        *(short4*)&Ah[r][c8]     = make_short4(hh[0], hh[1], hh[2], hh[3]);
        *(short4*)&Ah[r][c8 + 4] = make_short4(hh[4], hh[5], hh[6], hh[7]);
        *(short4*)&Al[r][c8]     = make_short4(ll[0], ll[1], ll[2], ll[3]);
        *(short4*)&Al[r][c8 + 4] = make_short4(ll[4], ll[5], ll[6], ll[7]);
    }
    __syncthreads();

    constexpr int NT = LDN / 32;
    const int w    = t >> 6;
    const int lane = t & 63;
    const int rg = w & 1, cg = w >> 1;
    const int lrow = lane & 15;
    const int lk   = (lane >> 4) << 3;
    const int colbase = cg * (16 * NT);

    f32x4 acc[NT];
#pragma unroll
    for (int n = 0; n < NT; ++n) acc[n] = (f32x4){0.f, 0.f, 0.f, 0.f};

#pragma unroll
    for (int ks = 0; ks < 4; ++ks) {
        const int k = ks * 32 + lk;
        const bf16x8 ah = *(const bf16x8*)&Ah[rg * 16 + lrow][k];
        const bf16x8 al = *(const bf16x8*)&Al[rg * 16 + lrow][k];
#pragma unroll
        for (int n = 0; n < NT; ++n) {
            const int col = colbase + n * 16 + lrow;
            const bf16x8 bh = *(const bf16x8*)(Wth + (size_t)col * 128 + k);
            const bf16x8 bl = *(const bf16x8*)(Wtl + (size_t)col * 128 + k);
            acc[n] = __builtin_amdgcn_mfma_f32_16x16x32_bf16(ah, bh, acc[n], 0, 0, 0);
            acc[n] = __builtin_amdgcn_mfma_f32_16x16x32_bf16(ah, bl, acc[n], 0, 0, 0);
            acc[n] = __builtin_amdgcn_mfma_f32_16x16x32_bf16(al, bh, acc[n], 0, 0, 0);
        }
    }

#pragma unroll
    for (int n = 0; n < NT; ++n) {
#pragma unroll
        for (int i = 0; i < 4; ++i) {
            const int r = row0 + rg * 16 + ((lane >> 4) << 2) + i;
            if (r < N)
                Y[(long long)r * LDN + colbase + n * 16 + lrow] = __float2half(acc[n][i]);
        }
    }
}

// ---------------------------------------------------------------- CSR gather (fp16 rows, fp32 accum)
// One wave per destination node; 8 halves (16B) per lane; 8-deep MLP unroll.
// SRCSCALE: multiply each source row by inv_src[s] (moves the x*inv_out
// pre-scale of layer 1 into the gather, per-edge).
template<int D, bool RELU, bool SRCSCALE, typename TO>
__launch_bounds__(256)
__global__ void k_gather(const int* __restrict__ rowptr, const unsigned short* __restrict__ csr_src,
                         const __half* __restrict__ Y, const float* __restrict__ inv_in,
                         const float* __restrict__ inv_out, const float* __restrict__ b,
                         TO* __restrict__ out, int N, const float* __restrict__ inv_src) {
    const int wid  = (int)((blockIdx.x * 256u + threadIdx.x) >> 6);
    const int lane = threadIdx.x & 63;
    if (wid >= N) return;

    const int start = rowptr[wid];
    const int end   = rowptr[wid + 1];

    constexpr int LPE = D / 8;            // lanes per edge (16 or 8)
    constexpr int EPW = 64 / LPE;         // edges per group (4 or 8)
    const int grp  = lane / LPE;
    const int colh = (lane % LPE) * 8;

    float a[8];
#pragma unroll
    for (int u = 0; u < 8; ++u) a[u] = 0.0f;

    auto accum = [&](uint4 raw, float io) {
        const __half2* h = (const __half2*)&raw;
#pragma unroll
        for (int u = 0; u < 4; ++u) {
            const float2 f = __half22float2(h[u]);
            if constexpr (SRCSCALE) {
                a[2 * u]     += f.x * io;
                a[2 * u + 1] += f.y * io;
            } else {
                a[2 * u]     += f.x;
                a[2 * u + 1] += f.y;
            }
        }
    };

    for (int k = start; k < end; k += 64) {
        const int idx = k + lane;
        const int sv  = (idx < end) ? (int)csr_src[idx] : 0;
        const int cnt = min(64, end - k);
        int j = 0;
        for (; j + 8 * EPW <= cnt; j += 8 * EPW) {
            int s[8];
#pragma unroll
            for (int u = 0; u < 8; ++u) s[u] = __shfl(sv, j + u * EPW + grp);
            uint4 r[8];
#pragma unroll
            for (int u = 0; u < 8; ++u) r[u] = *(const uint4*)(Y + (long long)s[u] * D + colh);
            float io[8];
            if constexpr (SRCSCALE) {
#pragma unroll
                for (int u = 0; u < 8; ++u) io[u] = inv_src[s[u]];
            }
#pragma unroll
            for (int u = 0; u < 8; ++u) accum(r[u], SRCSCALE ? io[u] : 0.0f);
        }
        for (; j + 4 * EPW <= cnt; j += 4 * EPW) {
            int s[4];
#pragma unroll
            for (int u = 0; u < 4; ++u) s[u] = __shfl(sv, j + u * EPW + grp);
            uint4 r[4];
#pragma unroll
            for (int u = 0; u < 4; ++u) r[u] = *(const uint4*)(Y + (long long)s[u] * D + colh);
            float io[4];
            if constexpr (SRCSCALE) {
#pragma unroll
                for (int u = 0; u < 4; ++u) io[u] = inv_src[s[u]];
            }
#pragma unroll
            for (int u = 0; u < 4; ++u) accum(r[u], SRCSCALE ? io[u] : 0.0f);
        }
        for (; j < cnt; j += EPW) {
            const int jj = j + grp;
            const int s  = __shfl(sv, jj);
            if (jj < cnt) {
                const uint4 r = *(const uint4*)(Y + (long long)s * D + colh);
                accum(r, SRCSCALE ? inv_src[s] : 0.0f);
            }
        }
    }

#pragma unroll
    for (int u = 0; u < 8; ++u) a[u] += __shfl_down(a[u], 32);
#pragma unroll
    for (int u = 0; u < 8; ++u) a[u] += __shfl_down(a[u], 16);
    if (EPW == 8) {
#pragma unroll
        for (int u = 0; u < 8; ++u) a[u] += __shfl_down(a[u], 8);
    }

    if (lane < LPE) {
        const float ii = inv_in[wid];
        const float io = RELU ? inv_out[wid] : 0.0f;
        const float4 b0 = *(const float4*)(b + colh);
        const float4 b1 = *(const float4*)(b + colh + 4);
        float r[8];
        r[0] = a[0] * ii + b0.x; r[1] = a[1] * ii + b0.y;
        r[2] = a[2] * ii + b0.z; r[3] = a[3] * ii + b0.w;
        r[4] = a[4] * ii + b1.x; r[5] = a[5] * ii + b1.y;
        r[6] = a[6] * ii + b1.z; r[7] = a[7] * ii + b1.w;
        if (RELU) {
#pragma unroll
            for (int u = 0; u < 8; ++u) r[u] = fmaxf(r[u], 0.0f) * io;
        }
        if constexpr (sizeof(TO) == 2) {
            __half2 h0 = __float22half2_rn(make_float2(r[0], r[1]));
            __half2 h1 = __float22half2_rn(make_float2(r[2], r[3]));
            __half2 h2 = __float22half2_rn(make_float2(r[4], r[5]));
            __half2 h3 = __float22half2_rn(make_float2(r[6], r[7]));
            uint4 pk;
            pk.x = *(unsigned int*)&h0; pk.y = *(unsigned int*)&h1;
            pk.z = *(unsigned int*)&h2; pk.w = *(unsigned int*)&h3;
            *(uint4*)((__half*)out + (long long)wid * D + colh) = pk;
        } else {
            float* o = (float*)out + (long long)wid * D + colh;
            *(float4*)(o)     = make_float4(r[0], r[1], r[2], r[3]);
            *(float4*)(o + 4) = make_float4(r[4], r[5], r[6], r[7]);
        }
    }
}

// ---------------------------------------------------------------- launch
extern "C" void kernel_launch(void* const* d_in, const int* in_sizes, int n_in,
                              void* d_out, int out_size, void* d_ws, size_t ws_size,
                              hipStream_t stream) {
    const int*   src = (const int*)d_in[0];
    const int*   dst = (const int*)d_in[1];
    const float* x   = (const float*)d_in[2];
    const float* W1  = (const float*)d_in[3];
    const float* b1  = (const float*)d_in[4];
    const float* W2  = (const float*)d_in[5];
    const float* b2  = (const float*)d_in[6];
    float* out = (float*)d_out;

    const int E  = in_sizes[0];
    const int N  = in_sizes[2] / D_IN;
    const int NB = (N + 127) >> 7;                 // 128-node buckets (<= NBMAX)
    const int mean = E / NB;
    const int cap  = mean + mean / 4 + 128;        // generous multinomial margin

    char* ws = (char*)d_ws;
    size_t off = 0;
    auto alloc = [&](size_t bytes) -> void* {
        void* p = ws + off;
        off += (bytes + 255) & ~(size_t)255;
        return p;
    };
    float*          inv_out = (float*)alloc((size_t)N * 4);
    float*          inv_in  = (float*)alloc((size_t)N * 4);
    int*            rowptr  = (int*)alloc((size_t)(N + 1) * 4);
    int*            cntD    = (int*)alloc((size_t)NB * 4);
    int*            cntS    = (int*)alloc((size_t)NB * 4);
    unsigned int*   storeD  = (unsigned int*)alloc((size_t)NB * cap * 4);
    unsigned char*  storeS  = (unsigned char*)alloc((size_t)NB * cap);
    unsigned short* csr_src = (unsigned short*)alloc((size_t)E * 2);
    unsigned short* W1h     = (unsigned short*)alloc(128 * 128 * 2);
    unsigned short* W1l     = (unsigned short*)alloc(128 * 128 * 2);
    unsigned short* W2h     = (unsigned short*)alloc(64 * 128 * 2);
    unsigned short* W2l     = (unsigned short*)alloc(64 * 128 * 2);
    __half*         Y1      = (__half*)alloc((size_t)N * D_HID * 2);
    __half*         H       = (__half*)alloc((size_t)N * D_HID * 2);
    __half*         Y2      = (__half*)alloc((size_t)N * D_OUT * 2);
    (void)ws_size; (void)n_in; (void)out_size;

    const int nbBlk   = (E + CHUNK - 1) / CHUNK;
    const int gemmBlk = (N + 31) / 32;

    // prep (W split + counter zero); then sort pass 1 OVERLAPPED with gemm1
    k_prep<<<97, 256, 0, stream>>>(W1, W2, W1h, W1l, W2h, W2l, cntD, cntS, NB);
    k_bucket_gemm<<<nbBlk + gemmBlk, 256, 0, stream>>>(src, dst, E, NB, cap, cntD, cntS,
                                                       storeD, storeS, x, W1h, W1l, Y1, N, nbBlk);
    k_fin<<<NB, 256, 0, stream>>>(storeD, storeS, cntD, cntS, cap, N, NB, E,
                                  rowptr, inv_in, inv_out, csr_src);

    // layer 1 aggregate: H = (half) relu((sum inv_out[s]*Y1[s])*inv_in + b1) * inv_out
    k_gather<D_HID, true, true, __half><<<(N + 3) / 4, 256, 0, stream>>>(
        rowptr, csr_src, Y1, inv_in, inv_out, b1, H, N, inv_out);

    // layer 2: Y2 = H@W2 ; out = gather(Y2)*inv_in + b2
    k_gemm_mfma<D_OUT><<<(N + 31) / 32, 256, 0, stream>>>(H, W2h, W2l, Y2, N);
    k_gather<D_OUT, false, false, float><<<(N + 3) / 4, 256, 0, stream>>>(
        rowptr, csr_src, Y2, inv_in, nullptr, b2, out, N, nullptr);
}